// Round 3
// baseline (51.788 us; speedup 1.0000x reference)
//
#include <hip/hip_runtime.h>

// BasisVQ: quantized[b,k,:] = basis[argmax_c latent[b,k,c], :]
//          indices[b,k]     = argmax_c latent[b,k,c]
// B=16, K=2048, C=1024, D=900. Output = [quantized (B*K*D f32), indices (B*K as f32)].
//
// R3: split into two pure-stream kernels.
//   K1 (argmax): pure read stream of latent (134 MB) -> 128 KB float indices.
//   K2 (gather): read idx + L2-resident basis (3.6 MB) -> pure write stream (118 MB).
// Rationale: mixed fine-grain read/write with a dependent gather in one kernel
// ran at 5.07 TB/s; pure streams run at 6.5-7.2 TB/s on this chip.

#define C_DIM 1024
#define D_DIM 900

typedef float vfloat4 __attribute__((ext_vector_type(4)));

// ---------------- Kernel 1: per-row argmax (one wave per row) ----------------
__global__ __launch_bounds__(256) void argmax_kernel(
    const float* __restrict__ latent,   // [ROWS, 1024]
    float* __restrict__ out_idx,        // [ROWS] (float-encoded int)
    int rows)
{
    const int lane = threadIdx.x & 63;
    const int wid  = threadIdx.x >> 6;
    const int row  = blockIdx.x * 4 + wid;
    if (row >= rows) return;

    const vfloat4* lrow = reinterpret_cast<const vfloat4*>(latent + (size_t)row * C_DIM);
    vfloat4 v0 = __builtin_nontemporal_load(&lrow[lane]);
    vfloat4 v1 = __builtin_nontemporal_load(&lrow[lane + 64]);
    vfloat4 v2 = __builtin_nontemporal_load(&lrow[lane + 128]);
    vfloat4 v3 = __builtin_nontemporal_load(&lrow[lane + 192]);

    // per-lane argmax, first-index-wins (ascending scan, strict >)
    float m = v0[0];
    int   mi = lane * 4;
    #pragma unroll
    for (int e = 1; e < 4; ++e)
        if (v0[e] > m) { m = v0[e]; mi = lane * 4 + e; }
    #pragma unroll
    for (int e = 0; e < 4; ++e)
        if (v1[e] > m) { m = v1[e]; mi = (64 + lane) * 4 + e; }
    #pragma unroll
    for (int e = 0; e < 4; ++e)
        if (v2[e] > m) { m = v2[e]; mi = (128 + lane) * 4 + e; }
    #pragma unroll
    for (int e = 0; e < 4; ++e)
        if (v3[e] > m) { m = v3[e]; mi = (192 + lane) * 4 + e; }

    // wave butterfly argmax, tie -> lowest index (matches jnp.argmax)
    #pragma unroll
    for (int off = 32; off > 0; off >>= 1) {
        float om = __shfl_xor(m, off, 64);
        int   oi = __shfl_xor(mi, off, 64);
        if (om > m || (om == m && oi < mi)) { m = om; mi = oi; }
    }

    if (lane == 0) __builtin_nontemporal_store((float)mi, &out_idx[row]);
}

// ---------------- Kernel 2: row gather (one wave per row) ----------------
__global__ __launch_bounds__(256) void gather_kernel(
    const float* __restrict__ basis,    // [1024, 900] (L2-resident, 3.6 MB)
    const float* __restrict__ out_idx,  // [ROWS]
    float* __restrict__ out_q,          // [ROWS, 900]
    int rows)
{
    const int lane = threadIdx.x & 63;
    const int wid  = threadIdx.x >> 6;
    const int row  = blockIdx.x * 4 + wid;
    if (row >= rows) return;

    // wave-uniform index (all lanes load same dword -> single fetch)
    const int idx = (int)out_idx[row];

    const vfloat4* b4 = reinterpret_cast<const vfloat4*>(basis + (size_t)idx * D_DIM);
    vfloat4*       o4 = reinterpret_cast<vfloat4*>(out_q + (size_t)row * D_DIM);
    #pragma unroll
    for (int j = 0; j < 4; ++j) {
        int t = 64 * j + lane;
        if (t < 225) {
            vfloat4 bv = b4[t];                       // cacheable: keep basis in L2
            __builtin_nontemporal_store(bv, &o4[t]);  // stream out
        }
    }
}

extern "C" void kernel_launch(void* const* d_in, const int* in_sizes, int n_in,
                              void* d_out, int out_size, void* d_ws, size_t ws_size,
                              hipStream_t stream) {
    const float* latent = (const float*)d_in[0];   // 16*2048*1024
    const float* basis  = (const float*)d_in[1];   // 1024*900
    (void)n_in; (void)d_ws; (void)ws_size; (void)out_size;

    const int rows = in_sizes[0] / C_DIM;          // 32768
    float* out_q   = (float*)d_out;                // rows*900
    float* out_idx = (float*)d_out + (size_t)rows * D_DIM;

    const int blocks = (rows + 3) / 4;             // 4 rows (waves) per block
    argmax_kernel<<<blocks, 256, 0, stream>>>(latent, out_idx, rows);
    gather_kernel<<<blocks, 256, 0, stream>>>(basis, out_idx, out_q, rows);
}